// Round 13
// baseline (682.685 us; speedup 1.0000x reference)
//
#include <hip/hip_runtime.h>
#include <hip/hip_bf16.h>
#include <stdint.h>

// SimTransformer — fp32 I/O. R17: qk_mfma n-split 128->64 rows/block
// (grid 256->512, 2 blocks/CU). R16's qk was occupancy-starved at exactly
// 1 block/CU (22.5% occ, all pipes <17%, ~50% barrier-idle). Wave remap
// 4rgx2mg -> 2rgx4mg; per-CU LDS/MFMA totals unchanged; accumulation order
// per (row,m) identical -> bit-identical lists -> absmax stays 0.03125.
// proj_q16/proj_v16/norm_q/pv_mfma byte-identical to R16 (proven 490us).

typedef __bf16 bf16;
typedef __bf16 bf16x8 __attribute__((ext_vector_type(8)));
typedef _Float16 f16;
typedef _Float16 f16x8 __attribute__((ext_vector_type(8)));
typedef unsigned short u16x8 __attribute__((ext_vector_type(8)));
typedef float f4 __attribute__((ext_vector_type(4)));
typedef float f16v __attribute__((ext_vector_type(16)));

#define CAP2 512     // per-row per-m-half list cap (mean ~25/half)
#define QBAND 2e-4f  // borderline band around 0.1 (fp16 1-term sigma ~9e-6)
#define BCAPC 512    // borderline pairs per chunk (mean ~6 at 64 rows)

// Split two f4's into hi/lo f16x8 limbs. Direct lane assignment (legal).
#define SPLIT_HL(v0, v1, h, l)                                              \
    do {                                                                    \
        h[0] = (f16)v0.x; l[0] = (f16)((v0.x - (float)h[0]) * 2048.0f);     \
        h[1] = (f16)v0.y; l[1] = (f16)((v0.y - (float)h[1]) * 2048.0f);     \
        h[2] = (f16)v0.z; l[2] = (f16)((v0.z - (float)h[2]) * 2048.0f);     \
        h[3] = (f16)v0.w; l[3] = (f16)((v0.w - (float)h[3]) * 2048.0f);     \
        h[4] = (f16)v1.x; l[4] = (f16)((v1.x - (float)h[4]) * 2048.0f);     \
        h[5] = (f16)v1.y; l[5] = (f16)((v1.y - (float)h[5]) * 2048.0f);     \
        h[6] = (f16)v1.z; l[6] = (f16)((v1.z - (float)h[6]) * 2048.0f);     \
        h[7] = (f16)v1.w; l[7] = (f16)((v1.w - (float)h[7]) * 2048.0f);     \
    } while (0)

// ---------------------------------------------------------------------------
// K1 (R16, proven): Q[n,e] fp32 = X·W^T via 3-term split-fp16 MFMA.
// ---------------------------------------------------------------------------
__global__ __launch_bounds__(512) void proj_q16(const float* __restrict__ X,
                                                const float* __restrict__ W,
                                                float* __restrict__ Q) {
    __shared__ f16 Bh[2][128][128];   // 64 KB
    __shared__ f16 Bl[2][128][128];   // 64 KB
    const int t = threadIdx.x;
    const int wave = t >> 6, lane = t & 63;
    const int ln16 = lane & 15, hi4 = lane >> 4;
    const int rg = wave >> 1, mg = wave & 1;
    const int n0 = blockIdx.x * 64;

    f16x8 Ah[16], Al[16];
    {
        const size_t arow = (size_t)(n0 + rg * 16 + ln16) * 512;
#pragma unroll
        for (int s = 0; s < 16; ++s) {
            f4 x0 = *(const f4*)&X[arow + s * 32 + hi4 * 8];
            f4 x1 = *(const f4*)&X[arow + s * 32 + hi4 * 8 + 4];
            f16x8 h, l;
            SPLIT_HL(x0, x1, h, l);
            Ah[s] = h; Al[s] = l;
        }
    }

#pragma unroll
    for (int i = 0; i < 4; ++i) {
        int id = i * 512 + t, r = id >> 4, s = id & 15;
        f4 w0 = *(const f4*)&W[(size_t)r * 512 + s * 8];
        f4 w1 = *(const f4*)&W[(size_t)r * 512 + s * 8 + 4];
        f16x8 h, l;
        SPLIT_HL(w0, w1, h, l);
        *(f16x8*)&Bh[0][r][(s ^ (r & 15)) * 8] = h;
        *(f16x8*)&Bl[0][r][(s ^ (r & 15)) * 8] = l;
    }
    __syncthreads();

    for (int ch = 0; ch < 4; ++ch) {
        const int eb = ch * 128;
        f4 Shh[4] = {}, Smid[4] = {};
#pragma unroll
        for (int k0i = 0; k0i < 4; ++k0i) {
            const int buf = k0i & 1;
            const bool last = (ch == 3) && (k0i == 3);
            const int neb = (k0i < 3) ? eb : eb + 128;
            const int nkb = (k0i < 3) ? (k0i + 1) * 128 : 0;
            f4 Lw[8];
            if (!last) {                        // issue next-stage loads EARLY
#pragma unroll
                for (int i = 0; i < 4; ++i) {
                    int id = i * 512 + t, r = id >> 4, s = id & 15;
                    Lw[i * 2]     = *(const f4*)&W[(size_t)(neb + r) * 512 + nkb + s * 8];
                    Lw[i * 2 + 1] = *(const f4*)&W[(size_t)(neb + r) * 512 + nkb + s * 8 + 4];
                }
            }
#pragma unroll
            for (int kk = 0; kk < 4; ++kk) {
                const int s = k0i * 4 + kk;
                const f16x8 ah = Ah[s], al = Al[s];
#pragma unroll
                for (int tt = 0; tt < 4; ++tt) {
                    const int br = mg * 64 + tt * 16 + ln16;
                    const int sl = ((kk * 4 + hi4) ^ ln16) * 8;
                    f16x8 bh = *(const f16x8*)&Bh[buf][br][sl];
                    f16x8 bl = *(const f16x8*)&Bl[buf][br][sl];
                    Shh[tt]  = __builtin_amdgcn_mfma_f32_16x16x32_f16(ah, bh, Shh[tt], 0, 0, 0);
                    Smid[tt] = __builtin_amdgcn_mfma_f32_16x16x32_f16(al, bh, Smid[tt], 0, 0, 0);
                    Smid[tt] = __builtin_amdgcn_mfma_f32_16x16x32_f16(ah, bl, Smid[tt], 0, 0, 0);
                }
            }
            __syncthreads();           // all reads of Bs[buf^1] done
            if (!last) {
#pragma unroll
                for (int i = 0; i < 4; ++i) {
                    int id = i * 512 + t, r = id >> 4, s = id & 15;
                    f4 w0 = Lw[i * 2], w1 = Lw[i * 2 + 1];
                    f16x8 h, l;
                    SPLIT_HL(w0, w1, h, l);
                    *(f16x8*)&Bh[buf ^ 1][r][(s ^ (r & 15)) * 8] = h;
                    *(f16x8*)&Bl[buf ^ 1][r][(s ^ (r & 15)) * 8] = l;
                }
            }
            __syncthreads();           // staging writes visible
        }
#pragma unroll
        for (int tt = 0; tt < 4; ++tt) {
            const int ecol = eb + mg * 64 + tt * 16 + ln16;
#pragma unroll
            for (int i = 0; i < 4; ++i)
                Q[(size_t)(n0 + rg * 16 + hi4 * 4 + i) * 512 + ecol] =
                    Shh[tt][i] + Smid[tt][i] * (1.0f / 2048.0f);
        }
    }
}

// ---------------------------------------------------------------------------
// K1b (proven R13): VT[b][e][m] = (X Wv^T)[m,e] via fp16 MFMA.
// ---------------------------------------------------------------------------
__global__ __launch_bounds__(256) void proj_v16(const float* __restrict__ X,
                                                const float* __restrict__ W,
                                                bf16* __restrict__ VT) {
    __shared__ f16 Xs[128][256];   // 64 KB, slot-swizzled
    const int t = threadIdx.x;
    const int wave = t >> 6, lane = t & 63;
    const int lo = lane & 15, h = lane >> 4;
    const int m0g = blockIdx.x * 128;
    const int e0 = blockIdx.y * 64;
    const int b = m0g >> 12, ml = m0g & 4095;

    f16x8 A[16];
    {
        const size_t arow = (size_t)(e0 + wave * 16 + lo) * 512;
#pragma unroll
        for (int s = 0; s < 16; ++s) {
            f4 w0 = *(const f4*)&W[arow + s * 32 + h * 8];
            f4 w1 = *(const f4*)&W[arow + s * 32 + h * 8 + 4];
            f16x8 a;
            a[0] = (f16)w0.x; a[1] = (f16)w0.y; a[2] = (f16)w0.z; a[3] = (f16)w0.w;
            a[4] = (f16)w1.x; a[5] = (f16)w1.y; a[6] = (f16)w1.z; a[7] = (f16)w1.w;
            A[s] = a;
        }
    }

    f4 acc[8] = {};
    for (int ph = 0; ph < 2; ++ph) {
        __syncthreads();
#pragma unroll
        for (int i = 0; i < 16; ++i) {
            int id = i * 256 + t;
            int r = id >> 5, s8 = id & 31;
            f4 x0 = *(const f4*)&X[(size_t)(m0g + r) * 512 + ph * 256 + s8 * 8];
            f4 x1 = *(const f4*)&X[(size_t)(m0g + r) * 512 + ph * 256 + s8 * 8 + 4];
            f16x8 v;
            v[0] = (f16)x0.x; v[1] = (f16)x0.y; v[2] = (f16)x0.z; v[3] = (f16)x0.w;
            v[4] = (f16)x1.x; v[5] = (f16)x1.y; v[6] = (f16)x1.z; v[7] = (f16)x1.w;
            int sl = (s8 & 16) | ((s8 ^ r) & 15);
            *(f16x8*)&Xs[r][sl * 8] = v;
        }
        __syncthreads();
#pragma unroll
        for (int s = 0; s < 8; ++s) {
            const f16x8 a = A[ph * 8 + s];
#pragma unroll
            for (int jt = 0; jt < 8; ++jt) {
                int rr = jt * 16 + lo;
                int c8 = s * 4 + h;
                int sl = (c8 & 16) | ((c8 ^ rr) & 15);
                f16x8 bb = *(const f16x8*)&Xs[rr][sl * 8];
                acc[jt] = __builtin_amdgcn_mfma_f32_16x16x32_f16(a, bb, acc[jt], 0, 0, 0);
            }
        }
    }
#pragma unroll
    for (int jt = 0; jt < 8; ++jt)
#pragma unroll
        for (int r = 0; r < 4; ++r) {
            int e = e0 + wave * 16 + h * 4 + r;
            int m = ml + jt * 16 + lo;
            VT[((size_t)b * 512 + e) * 4096 + m] = (bf16)acc[jt][r];
        }
}

// ---------------------------------------------------------------------------
// K2 (proven R16): wave-per-row normalize, fp32 Q IN-PLACE + fp16 qh.
// ---------------------------------------------------------------------------
__global__ __launch_bounds__(256) void norm_q(float* __restrict__ Q,
                                              f16* __restrict__ QH) {
    const int wave = threadIdx.x >> 6, lane = threadIdx.x & 63;
    const int row = blockIdx.x * 4 + wave;
    float* q = Q + (size_t)row * 512;
    float x[8];
    double s = 0.0;
    for (int j = 0; j < 8; ++j) { x[j] = q[lane * 8 + j]; s += (double)x[j] * x[j]; }
    for (int off = 1; off < 64; off <<= 1) s += __shfl_xor(s, off);
    double nm = fmax(sqrt(s), 1e-12);
    for (int j = 0; j < 8; ++j) {
        float qf = (float)((double)x[j] / nm);
        q[lane * 8 + j] = qf;
        QH[(size_t)row * 512 + lane * 8 + j] = (f16)qf;
    }
}

// ---------------------------------------------------------------------------
// K3 (R17): 1-term fp16 MFMA cosine + narrow-band fp32 verify.
// grid 512, 512 thr, 2 blocks/CU. bid&7 -> (batch,half) XCD-pinned;
// bid>>3 -> 64-row n-tile. 8 waves = 2 row-groups x 4 m-groups.
// ---------------------------------------------------------------------------
__global__ __launch_bounds__(512, 4) void qk_mfma(const float* __restrict__ QF,
                                                  const f16* __restrict__ QHB,
                                                  uint16_t* __restrict__ counts,
                                                  uint16_t* __restrict__ idxs,
                                                  bf16* __restrict__ vals) {
    __shared__ f16 Bs[2][128][128];       // 64 KB, slot-swizzled
    __shared__ int cnt[64];
    __shared__ int bcnt;
    __shared__ uint32_t blist[BCAPC];     // 2 KB

    const int t = threadIdx.x;
    const int wave = t >> 6, lane = t & 63;
    const int ln16 = lane & 15, hi4 = lane >> 4;
    const int rg = wave >> 2, mg = wave & 3;
    const int grp = blockIdx.x & 7;            // one (batch,half) per XCD
    const int b = grp >> 1, half = grp & 1;
    const int n0 = (blockIdx.x >> 3) * 64;
    const size_t nb = (size_t)b * 4096;
    const float* qf = QF + nb * 512;
    const f16* qh = QHB + nb * 512;
    const int mbase = half * 2048;

    f16x8 A[2][16];
#pragma unroll
    for (int rt = 0; rt < 2; ++rt) {
        const size_t arow = (size_t)(n0 + rg * 32 + rt * 16 + ln16) * 512;
#pragma unroll
        for (int s = 0; s < 16; ++s)
            A[rt][s] = *(const f16x8*)&qh[arow + s * 32 + hi4 * 8];
    }

    if (t < 64) cnt[t] = 0;
    if (t == 0) bcnt = 0;

#pragma unroll
    for (int i = 0; i < 4; ++i) {
        int id = i * 512 + t, r = id >> 4, s = id & 15;
        *(f16x8*)&Bs[0][r][(s ^ (r & 15)) * 8] =
            *(const f16x8*)&qh[(size_t)(mbase + r) * 512 + s * 8];
    }
    __syncthreads();

    for (int ch = 0; ch < 16; ++ch) {
        const int mst = mbase + ch * 128;
        f4 S[2][2] = {};
#pragma unroll
        for (int k0i = 0; k0i < 4; ++k0i) {
            const int buf = k0i & 1;
            const bool last = (k0i == 3) && (ch == 15);
            const int nmst = (k0i < 3) ? mst : mst + 128;
            const int nk0 = (k0i < 3) ? (k0i + 1) * 128 : 0;
            f16x8 L[4];
            if (!last) {                        // issue next-step loads EARLY
#pragma unroll
                for (int i = 0; i < 4; ++i) {
                    int id = i * 512 + t, r = id >> 4, s = id & 15;
                    L[i] = *(const f16x8*)&qh[(size_t)(nmst + r) * 512 + nk0 + s * 8];
                }
            }
#pragma unroll
            for (int kk = 0; kk < 4; ++kk) {
                const int s = k0i * 4 + kk;
                const f16x8 a0 = A[0][s], a1 = A[1][s];
#pragma unroll
                for (int tt = 0; tt < 2; ++tt) {
                    const int br = mg * 32 + tt * 16 + ln16;
                    f16x8 bb = *(const f16x8*)&Bs[buf][br][((kk * 4 + hi4) ^ ln16) * 8];
                    S[0][tt] = __builtin_amdgcn_mfma_f32_16x16x32_f16(a0, bb, S[0][tt], 0, 0, 0);
                    S[1][tt] = __builtin_amdgcn_mfma_f32_16x16x32_f16(a1, bb, S[1][tt], 0, 0, 0);
                }
            }
            if (k0i == 3) {                     // chunk complete: threshold
#pragma unroll
                for (int rt = 0; rt < 2; ++rt)
#pragma unroll
                    for (int tt = 0; tt < 2; ++tt) {
                        const int m = mst + mg * 32 + tt * 16 + ln16;
#pragma unroll
                        for (int i = 0; i < 4; ++i) {
                            float cs = S[rt][tt][i];
                            int row = rg * 32 + rt * 16 + hi4 * 4 + i;
                            if (cs > 0.1f + QBAND) {
                                int pos = atomicAdd(&cnt[row], 1);
                                if (pos < CAP2) {
                                    size_t o = ((size_t)(nb + n0 + row) * 2 + half) * CAP2 + pos;
                                    idxs[o] = (uint16_t)m;
                                    vals[o] = (bf16)cs;
                                }
                            } else if (cs > 0.1f - QBAND) {
                                int bp = atomicAdd(&bcnt, 1);
                                if (bp < BCAPC)
                                    blist[bp] = ((uint32_t)row << 12) | (uint32_t)m;
                            }
                        }
                    }
            }
            __syncthreads();           // Bs[buf^1] reads done; blist complete
            if (!last) {
#pragma unroll
                for (int i = 0; i < 4; ++i) {
                    int id = i * 512 + t, r = id >> 4, s = id & 15;
                    *(f16x8*)&Bs[buf ^ 1][r][(s ^ (r & 15)) * 8] = L[i];
                }
            }
            if (k0i == 3) {            // wave-parallel fp32/f64-acc verify
                int nbd = bcnt; if (nbd > BCAPC) nbd = BCAPC;
                for (int p = wave; p < nbd; p += 8) {
                    uint32_t pk = blist[p];
                    int row = (int)(pk >> 12), m = (int)(pk & 4095);
                    const float* qa = qf + (size_t)(n0 + row) * 512;
                    const float* qc = qf + (size_t)m * 512;
                    f4 a0 = *(const f4*)&qa[lane * 8];
                    f4 a1 = *(const f4*)&qa[lane * 8 + 4];
                    f4 c0 = *(const f4*)&qc[lane * 8];
                    f4 c1 = *(const f4*)&qc[lane * 8 + 4];
                    double s = (double)a0.x * c0.x + (double)a0.y * c0.y +
                               (double)a0.z * c0.z + (double)a0.w * c0.w +
                               (double)a1.x * c1.x + (double)a1.y * c1.y +
                               (double)a1.z * c1.z + (double)a1.w * c1.w;
                    for (int off = 1; off < 64; off <<= 1) s += __shfl_xor(s, off);
                    if (lane == 0 && s > 0.1) {
                        int pos = atomicAdd(&cnt[row], 1);
                        if (pos < CAP2) {
                            size_t o = ((size_t)(nb + n0 + row) * 2 + half) * CAP2 + pos;
                            idxs[o] = (uint16_t)m;
                            vals[o] = (bf16)(float)s;
                        }
                    }
                }
            }
            __syncthreads();           // staging writes visible; verify done
            if (k0i == 3 && t == 0) bcnt = 0;
        }
    }
    __syncthreads();
    if (t < 64) {
        int c = cnt[t];
        counts[(size_t)(nb + n0 + t) * 2 + half] = (uint16_t)(c > CAP2 ? CAP2 : c);
    }
}

// ---------------------------------------------------------------------------
// K4 (R10, proven): 32x32x16-MFMA PV + fused LayerNorm. grid 256, 512 thr.
// ---------------------------------------------------------------------------
__global__ __launch_bounds__(512, 2) void pv_mfma(const bf16* __restrict__ VT,
                                                  const uint16_t* __restrict__ counts,
                                                  const uint16_t* __restrict__ idxs,
                                                  const bf16* __restrict__ vals,
                                                  const float* __restrict__ gamma,
                                                  const float* __restrict__ beta,
                                                  float* __restrict__ Out) {
    __shared__ __align__(16) char smemraw[147456];   // Vts 128K + Wsm 16K
    bf16 (*Vts)[128] = (bf16(*)[128])smemraw;        // [512 e][128 m] swz
    bf16 (*Wsm)[128] = (bf16(*)[128])(smemraw + 131072); // [64 n][128 m] swz

    const int t = threadIdx.x;
    const int wave = t >> 6, lane = t & 63;
    const int l31 = lane & 31, l15 = lane & 15, g = lane >> 5;
    const int grp = blockIdx.x & 7;                  // XCD-pinned batch panel
    const int b = grp >> 1;
    const int n0 = ((blockIdx.x >> 3) + ((grp & 1) ? 32 : 0)) * 64;
    const size_t nb = (size_t)b * 4096;
    const bf16* vtb = VT + (size_t)b * 512 * 4096;

    int myc0 = 0, myc1 = 0, cu = 0, pb = 0;
    u16x8 pi0 = {}, pi1 = {};
    bf16x8 pv0 = {}, pv1 = {};
    size_t base0 = 0, base1 = 0;
    if (t < 64) {
        myc0 = (int)counts[(size_t)(nb + n0 + t) * 2 + 0];
        myc1 = (int)counts[(size_t)(nb + n0 + t) * 2 + 1];
        if (myc0 > CAP2) myc0 = CAP2;
        if (myc1 > CAP2) myc1 = CAP2;
        base0 = ((size_t)(nb + n0 + t) * 2 + 0) * CAP2;
        base1 = ((size_t)(nb + n0 + t) * 2 + 1) * CAP2;
        pi0 = *(const u16x8*)&idxs[base0];
        pi1 = *(const u16x8*)&idxs[base0 + 8];
        pv0 = *(const bf16x8*)&vals[base0];
        pv1 = *(const bf16x8*)&vals[base0 + 8];
    }

    bf16x8 L[16];
#pragma unroll
    for (int i = 0; i < 16; ++i) {
        int id = i * 512 + t, r = id >> 4, s = id & 15;
        L[i] = *(const bf16x8*)&vtb[(size_t)r * 4096 + s * 8];
    }

    f16v acc[2][2] = {};   // [nt][et]

    for (int ch = 0; ch < 32; ++ch) {
        __syncthreads();
#pragma unroll
        for (int i = 0; i < 16; ++i) {
            int id = i * 512 + t, r = id >> 4, s = id & 15;
            *(bf16x8*)&Vts[r][(s ^ (r & 15)) << 3] = L[i];
        }
        if (t < 64) {
            bf16 z0 = (bf16)0.0f;
            bf16x8 zv = {z0, z0, z0, z0, z0, z0, z0, z0};
#pragma unroll
            for (int sj = 0; sj < 16; ++sj) *(bf16x8*)&Wsm[t][sj * 8] = zv;
            if (ch == 16) cu = 0;
            const int m0l = ch * 128;
            const int myc = (ch >= 16) ? myc1 : myc0;
            const size_t base = (ch >= 16) ? base1 : base0;
            int end = cu;
#pragma unroll
            for (int j = 0; j < 16; ++j) {
                int pos = pb + j;
                int mi = (j < 8) ? (int)pi0[j] : (int)pi1[j - 8];
                bf16 vv = (j < 8) ? pv0[j] : pv1[j - 8];
                if (pos == end && pos < myc && mi < m0l + 128) {
                    int lo = mi - m0l;
                    Wsm[t][(((lo >> 3) ^ (t & 15)) << 3) | (lo & 7)] = vv;
                    end = pos + 1;
                }
            }
            if (end == pb + 16) {
                while (end < myc) {
                    int mi = (int)idxs[base + end];
                    if (mi >= m0l + 128) break;
                    int lo = mi - m0l;
                    Wsm[t][(((lo >> 3) ^ (t & 15)) << 3) | (lo & 7)] =
                        vals[base + end];
                    ++end;
                }
            }
            cu = end;
        }
        __syncthreads();
        if (ch < 31) {
            const int mo = (ch + 1) * 128;
#pragma unroll
            for (int i = 0; i < 16; ++i) {
                int id = i * 512 + t, r = id >> 4, s = id & 15;
                L[i] = *(const bf16x8*)&vtb[(size_t)r * 4096 + mo + s * 8];
            }
            if (t < 64) {
                int ncu = (ch + 1 == 16) ? 0 : cu;
                const size_t nbase = (ch + 1 >= 16) ? base1 : base0;
                pb = ncu & ~7;
                pi0 = *(const u16x8*)&idxs[nbase + pb];
                pi1 = *(const u16x8*)&idxs[nbase + pb + 8];
                pv0 = *(const bf16x8*)&vals[nbase + pb];
                pv1 = *(const bf16x8*)&vals[nbase + pb + 8];
            }
        }
#pragma unroll
        for (int ks = 0; ks < 8; ++ks) {
            const int sw = (((ks * 2 + g) ^ l15) << 3);
            bf16x8 A0 = *(const bf16x8*)&Wsm[l31][sw];
            bf16x8 A1 = *(const bf16x8*)&Wsm[32 + l31][sw];
            bf16x8 B0 = *(const bf16x8*)&Vts[wave * 64 + l31][sw];
            bf16x8 B1 = *(const bf16x8*)&Vts[wave * 64 + 32 + l31][sw];
            acc[0][0] = __builtin_amdgcn_mfma_f32_32x32x16_bf16(A0, B0, acc[0][0], 0, 0, 0);
            acc[0][1] = __builtin_amdgcn_mfma_f32_32x32x16_bf16(A0, B1, acc[0][1], 0, 0, 0);
            acc[1][0] = __builtin_amdgcn_mfma_f32_32x32x16_bf16(A1, B0, acc[1][0], 0, 0, 0);
            acc[1][1] = __builtin_amdgcn_mfma_f32_32x32x16_bf16(A1, B1, acc[1][1], 0, 0, 0);
        }
    }

    // ---- fused LayerNorm over 512 cols ----
    __syncthreads();
    float* red = (float*)smemraw;            // [8][64][2]
    float* mrs = (float*)(smemraw + 4096);   // mu[64], rs[64]
#pragma unroll
    for (int nt = 0; nt < 2; ++nt)
#pragma unroll
        for (int r = 0; r < 16; ++r) {
            float v0 = acc[nt][0][r], v1 = acc[nt][1][r];
            float s = v0 + v1, q = v0 * v0 + v1 * v1;
            for (int off = 1; off < 32; off <<= 1) {
                s += __shfl_xor(s, off);
                q += __shfl_xor(q, off);
            }
            if (l31 == 0) {
                int nloc = nt * 32 + (r & 3) + 8 * (r >> 2) + 4 * g;
                red[(wave * 64 + nloc) * 2] = s;
                red[(wave * 64 + nloc) * 2 + 1] = q;
            }
        }
    __syncthreads();
    if (t < 64) {
        float s = 0.f, q = 0.f;
        for (int w2 = 0; w2 < 8; ++w2) {
            s += red[(w2 * 64 + t) * 2];
            q += red[(w2 * 64 + t) * 2 + 1];
        }
        float mu = s * (1.0f / 512.0f);
        float var = q * (1.0f / 512.0f) - mu * mu;
        mrs[t] = mu;
        mrs[64 + t] = rsqrtf(var + 1e-5f);
    }
    __syncthreads();
    const float g0 = gamma[wave * 64 + l31], g1 = gamma[wave * 64 + 32 + l31];
    const float b0 = beta[wave * 64 + l31], b1 = beta[wave * 64 + 32 + l31];
#pragma unroll
    for (int nt = 0; nt < 2; ++nt)
#pragma unroll
        for (int r = 0; r < 16; ++r) {
            int nloc = nt * 32 + (r & 3) + 8 * (r >> 2) + 4 * g;
            float mu = mrs[nloc], rs = mrs[64 + nloc];
            size_t ro = (nb + n0 + nloc) * 512;
            float y0 = (acc[nt][0][r] - mu) * rs * g0 + b0;
            float y1 = (acc[nt][1][r] - mu) * rs * g1 + b1;
            Out[ro + wave * 64 + l31] = y0;
            Out[ro + wave * 64 + 32 + l31] = y1;
        }
}

// ---------------------------------------------------------------------------
extern "C" void kernel_launch(void* const* d_in, const int* in_sizes, int n_in,
                              void* d_out, int out_size, void* d_ws, size_t ws_size,
                              hipStream_t stream) {
    const float* x     = (const float*)d_in[0];
    const float* wqk   = (const float*)d_in[1];
    const float* wv    = (const float*)d_in[2];
    const float* gamma = (const float*)d_in[3];
    const float* beta  = (const float*)d_in[4];
    float* out = (float*)d_out;

    char* ws = (char*)d_ws;
    uint16_t* idxs   = (uint16_t*)ws;                        // 33,554,432 B
    bf16*     vals   = (bf16*)(ws + 33554432);               // -> 67,108,864
    float*    qn32   = (float*)(ws + 67108864);              // -> 100,663,296 (Q fp32, normalized in-place)
    f16*      qh16   = (f16*)(ws + 100663296);               // -> 117,440,512
    // [117,440,512 .. 134,217,728) dead
    bf16*     vt     = (bf16*)(ws + 134217728);              // -> 150,994,944
    uint16_t* counts = (uint16_t*)(ws + 150994944);          // -> 151,060,480
    const size_t need = 151060480;  // == R2-proven ws_size lower bound
    if (ws_size < need) return;

    proj_q16<<<256, 512, 0, stream>>>(x, wqk, qn32);
    proj_v16<<<dim3(128, 8), 256, 0, stream>>>(x, wv, vt);
    norm_q<<<4096, 256, 0, stream>>>(qn32, qh16);
    qk_mfma<<<512, 512, 0, stream>>>(qn32, qh16, counts, idxs, vals);
    pv_mfma<<<256, 512, 0, stream>>>(vt, counts, idxs, vals, gamma, beta, out);
}

// Round 14
// 526.476 us; speedup vs baseline: 1.2967x; 1.2967x over previous
//
#include <hip/hip_runtime.h>
#include <hip/hip_bf16.h>
#include <stdint.h>

// SimTransformer — fp32 I/O. R18: R17's 2-blocks/CU qk partition kept
// (64-row blocks, grid 512 — correct, passed) but the launch_bounds(512,4)
// hint REMOVED (it capped VGPR at 64 vs demand ~176 -> A spilled to scratch
// -> 817MB FETCH, 356us). A is no longer register-resident full-K: per k0i
// step, load Ah0[4]/Ah1[4] (32 VGPR) from L2-hot qh rows. Natural demand
// ~110-120 <= 128 -> 4 waves/SIMD -> 2 blocks/CU from ACTUAL allocation.
// MFMA order identical -> bit-identical lists -> absmax 0.03125.
// proj_q16/proj_v16/norm_q/pv_mfma byte-identical to R16 (proven 490us).

typedef __bf16 bf16;
typedef __bf16 bf16x8 __attribute__((ext_vector_type(8)));
typedef _Float16 f16;
typedef _Float16 f16x8 __attribute__((ext_vector_type(8)));
typedef unsigned short u16x8 __attribute__((ext_vector_type(8)));
typedef float f4 __attribute__((ext_vector_type(4)));
typedef float f16v __attribute__((ext_vector_type(16)));

#define CAP2 512     // per-row per-m-half list cap (mean ~25/half)
#define QBAND 2e-4f  // borderline band around 0.1 (fp16 1-term sigma ~9e-6)
#define BCAPC 512    // borderline pairs per chunk (mean ~6 at 64 rows)

// Split two f4's into hi/lo f16x8 limbs. Direct lane assignment (legal).
#define SPLIT_HL(v0, v1, h, l)                                              \
    do {                                                                    \
        h[0] = (f16)v0.x; l[0] = (f16)((v0.x - (float)h[0]) * 2048.0f);     \
        h[1] = (f16)v0.y; l[1] = (f16)((v0.y - (float)h[1]) * 2048.0f);     \
        h[2] = (f16)v0.z; l[2] = (f16)((v0.z - (float)h[2]) * 2048.0f);     \
        h[3] = (f16)v0.w; l[3] = (f16)((v0.w - (float)h[3]) * 2048.0f);     \
        h[4] = (f16)v1.x; l[4] = (f16)((v1.x - (float)h[4]) * 2048.0f);     \
        h[5] = (f16)v1.y; l[5] = (f16)((v1.y - (float)h[5]) * 2048.0f);     \
        h[6] = (f16)v1.z; l[6] = (f16)((v1.z - (float)h[6]) * 2048.0f);     \
        h[7] = (f16)v1.w; l[7] = (f16)((v1.w - (float)h[7]) * 2048.0f);     \
    } while (0)

// ---------------------------------------------------------------------------
// K1 (R16, proven): Q[n,e] fp32 = X·W^T via 3-term split-fp16 MFMA.
// ---------------------------------------------------------------------------
__global__ __launch_bounds__(512) void proj_q16(const float* __restrict__ X,
                                                const float* __restrict__ W,
                                                float* __restrict__ Q) {
    __shared__ f16 Bh[2][128][128];   // 64 KB
    __shared__ f16 Bl[2][128][128];   // 64 KB
    const int t = threadIdx.x;
    const int wave = t >> 6, lane = t & 63;
    const int ln16 = lane & 15, hi4 = lane >> 4;
    const int rg = wave >> 1, mg = wave & 1;
    const int n0 = blockIdx.x * 64;

    f16x8 Ah[16], Al[16];
    {
        const size_t arow = (size_t)(n0 + rg * 16 + ln16) * 512;
#pragma unroll
        for (int s = 0; s < 16; ++s) {
            f4 x0 = *(const f4*)&X[arow + s * 32 + hi4 * 8];
            f4 x1 = *(const f4*)&X[arow + s * 32 + hi4 * 8 + 4];
            f16x8 h, l;
            SPLIT_HL(x0, x1, h, l);
            Ah[s] = h; Al[s] = l;
        }
    }

#pragma unroll
    for (int i = 0; i < 4; ++i) {
        int id = i * 512 + t, r = id >> 4, s = id & 15;
        f4 w0 = *(const f4*)&W[(size_t)r * 512 + s * 8];
        f4 w1 = *(const f4*)&W[(size_t)r * 512 + s * 8 + 4];
        f16x8 h, l;
        SPLIT_HL(w0, w1, h, l);
        *(f16x8*)&Bh[0][r][(s ^ (r & 15)) * 8] = h;
        *(f16x8*)&Bl[0][r][(s ^ (r & 15)) * 8] = l;
    }
    __syncthreads();

    for (int ch = 0; ch < 4; ++ch) {
        const int eb = ch * 128;
        f4 Shh[4] = {}, Smid[4] = {};
#pragma unroll
        for (int k0i = 0; k0i < 4; ++k0i) {
            const int buf = k0i & 1;
            const bool last = (ch == 3) && (k0i == 3);
            const int neb = (k0i < 3) ? eb : eb + 128;
            const int nkb = (k0i < 3) ? (k0i + 1) * 128 : 0;
            f4 Lw[8];
            if (!last) {                        // issue next-stage loads EARLY
#pragma unroll
                for (int i = 0; i < 4; ++i) {
                    int id = i * 512 + t, r = id >> 4, s = id & 15;
                    Lw[i * 2]     = *(const f4*)&W[(size_t)(neb + r) * 512 + nkb + s * 8];
                    Lw[i * 2 + 1] = *(const f4*)&W[(size_t)(neb + r) * 512 + nkb + s * 8 + 4];
                }
            }
#pragma unroll
            for (int kk = 0; kk < 4; ++kk) {
                const int s = k0i * 4 + kk;
                const f16x8 ah = Ah[s], al = Al[s];
#pragma unroll
                for (int tt = 0; tt < 4; ++tt) {
                    const int br = mg * 64 + tt * 16 + ln16;
                    const int sl = ((kk * 4 + hi4) ^ ln16) * 8;
                    f16x8 bh = *(const f16x8*)&Bh[buf][br][sl];
                    f16x8 bl = *(const f16x8*)&Bl[buf][br][sl];
                    Shh[tt]  = __builtin_amdgcn_mfma_f32_16x16x32_f16(ah, bh, Shh[tt], 0, 0, 0);
                    Smid[tt] = __builtin_amdgcn_mfma_f32_16x16x32_f16(al, bh, Smid[tt], 0, 0, 0);
                    Smid[tt] = __builtin_amdgcn_mfma_f32_16x16x32_f16(ah, bl, Smid[tt], 0, 0, 0);
                }
            }
            __syncthreads();           // all reads of Bs[buf^1] done
            if (!last) {
#pragma unroll
                for (int i = 0; i < 4; ++i) {
                    int id = i * 512 + t, r = id >> 4, s = id & 15;
                    f4 w0 = Lw[i * 2], w1 = Lw[i * 2 + 1];
                    f16x8 h, l;
                    SPLIT_HL(w0, w1, h, l);
                    *(f16x8*)&Bh[buf ^ 1][r][(s ^ (r & 15)) * 8] = h;
                    *(f16x8*)&Bl[buf ^ 1][r][(s ^ (r & 15)) * 8] = l;
                }
            }
            __syncthreads();           // staging writes visible
        }
#pragma unroll
        for (int tt = 0; tt < 4; ++tt) {
            const int ecol = eb + mg * 64 + tt * 16 + ln16;
#pragma unroll
            for (int i = 0; i < 4; ++i)
                Q[(size_t)(n0 + rg * 16 + hi4 * 4 + i) * 512 + ecol] =
                    Shh[tt][i] + Smid[tt][i] * (1.0f / 2048.0f);
        }
    }
}

// ---------------------------------------------------------------------------
// K1b (proven R13): VT[b][e][m] = (X Wv^T)[m,e] via fp16 MFMA.
// ---------------------------------------------------------------------------
__global__ __launch_bounds__(256) void proj_v16(const float* __restrict__ X,
                                                const float* __restrict__ W,
                                                bf16* __restrict__ VT) {
    __shared__ f16 Xs[128][256];   // 64 KB, slot-swizzled
    const int t = threadIdx.x;
    const int wave = t >> 6, lane = t & 63;
    const int lo = lane & 15, h = lane >> 4;
    const int m0g = blockIdx.x * 128;
    const int e0 = blockIdx.y * 64;
    const int b = m0g >> 12, ml = m0g & 4095;

    f16x8 A[16];
    {
        const size_t arow = (size_t)(e0 + wave * 16 + lo) * 512;
#pragma unroll
        for (int s = 0; s < 16; ++s) {
            f4 w0 = *(const f4*)&W[arow + s * 32 + h * 8];
            f4 w1 = *(const f4*)&W[arow + s * 32 + h * 8 + 4];
            f16x8 a;
            a[0] = (f16)w0.x; a[1] = (f16)w0.y; a[2] = (f16)w0.z; a[3] = (f16)w0.w;
            a[4] = (f16)w1.x; a[5] = (f16)w1.y; a[6] = (f16)w1.z; a[7] = (f16)w1.w;
            A[s] = a;
        }
    }

    f4 acc[8] = {};
    for (int ph = 0; ph < 2; ++ph) {
        __syncthreads();
#pragma unroll
        for (int i = 0; i < 16; ++i) {
            int id = i * 256 + t;
            int r = id >> 5, s8 = id & 31;
            f4 x0 = *(const f4*)&X[(size_t)(m0g + r) * 512 + ph * 256 + s8 * 8];
            f4 x1 = *(const f4*)&X[(size_t)(m0g + r) * 512 + ph * 256 + s8 * 8 + 4];
            f16x8 v;
            v[0] = (f16)x0.x; v[1] = (f16)x0.y; v[2] = (f16)x0.z; v[3] = (f16)x0.w;
            v[4] = (f16)x1.x; v[5] = (f16)x1.y; v[6] = (f16)x1.z; v[7] = (f16)x1.w;
            int sl = (s8 & 16) | ((s8 ^ r) & 15);
            *(f16x8*)&Xs[r][sl * 8] = v;
        }
        __syncthreads();
#pragma unroll
        for (int s = 0; s < 8; ++s) {
            const f16x8 a = A[ph * 8 + s];
#pragma unroll
            for (int jt = 0; jt < 8; ++jt) {
                int rr = jt * 16 + lo;
                int c8 = s * 4 + h;
                int sl = (c8 & 16) | ((c8 ^ rr) & 15);
                f16x8 bb = *(const f16x8*)&Xs[rr][sl * 8];
                acc[jt] = __builtin_amdgcn_mfma_f32_16x16x32_f16(a, bb, acc[jt], 0, 0, 0);
            }
        }
    }
#pragma unroll
    for (int jt = 0; jt < 8; ++jt)
#pragma unroll
        for (int r = 0; r < 4; ++r) {
            int e = e0 + wave * 16 + h * 4 + r;
            int m = ml + jt * 16 + lo;
            VT[((size_t)b * 512 + e) * 4096 + m] = (bf16)acc[jt][r];
        }
}

// ---------------------------------------------------------------------------
// K2 (proven R16): wave-per-row normalize, fp32 Q IN-PLACE + fp16 qh.
// ---------------------------------------------------------------------------
__global__ __launch_bounds__(256) void norm_q(float* __restrict__ Q,
                                              f16* __restrict__ QH) {
    const int wave = threadIdx.x >> 6, lane = threadIdx.x & 63;
    const int row = blockIdx.x * 4 + wave;
    float* q = Q + (size_t)row * 512;
    float x[8];
    double s = 0.0;
    for (int j = 0; j < 8; ++j) { x[j] = q[lane * 8 + j]; s += (double)x[j] * x[j]; }
    for (int off = 1; off < 64; off <<= 1) s += __shfl_xor(s, off);
    double nm = fmax(sqrt(s), 1e-12);
    for (int j = 0; j < 8; ++j) {
        float qf = (float)((double)x[j] / nm);
        q[lane * 8 + j] = qf;
        QH[(size_t)row * 512 + lane * 8 + j] = (f16)qf;
    }
}

// ---------------------------------------------------------------------------
// K3 (R18): 1-term fp16 MFMA cosine + narrow-band fp32 verify.
// grid 512, 512 thr. 64-row blocks; 8 waves = 2rg x 4mg. A slices loaded
// per k0i from L2-hot qh (32 VGPR) — no full-K register residency, no hint.
// ---------------------------------------------------------------------------
__global__ __launch_bounds__(512) void qk_mfma(const float* __restrict__ QF,
                                               const f16* __restrict__ QHB,
                                               uint16_t* __restrict__ counts,
                                               uint16_t* __restrict__ idxs,
                                               bf16* __restrict__ vals) {
    __shared__ f16 Bs[2][128][128];       // 64 KB, slot-swizzled
    __shared__ int cnt[64];
    __shared__ int bcnt;
    __shared__ uint32_t blist[BCAPC];     // 2 KB

    const int t = threadIdx.x;
    const int wave = t >> 6, lane = t & 63;
    const int ln16 = lane & 15, hi4 = lane >> 4;
    const int rg = wave >> 2, mg = wave & 3;
    const int grp = blockIdx.x & 7;            // one (batch,half) per XCD
    const int b = grp >> 1, half = grp & 1;
    const int n0 = (blockIdx.x >> 3) * 64;
    const size_t nb = (size_t)b * 4096;
    const float* qf = QF + nb * 512;
    const f16* qh = QHB + nb * 512;
    const int mbase = half * 2048;

    const size_t arow0 = (size_t)(n0 + rg * 32 + ln16) * 512 + hi4 * 8;
    const size_t arow1 = (size_t)(n0 + rg * 32 + 16 + ln16) * 512 + hi4 * 8;

    if (t < 64) cnt[t] = 0;
    if (t == 0) bcnt = 0;

#pragma unroll
    for (int i = 0; i < 4; ++i) {
        int id = i * 512 + t, r = id >> 4, s = id & 15;
        *(f16x8*)&Bs[0][r][(s ^ (r & 15)) * 8] =
            *(const f16x8*)&qh[(size_t)(mbase + r) * 512 + s * 8];
    }
    __syncthreads();

    for (int ch = 0; ch < 16; ++ch) {
        const int mst = mbase + ch * 128;
        f4 S[2][2] = {};
#pragma unroll
        for (int k0i = 0; k0i < 4; ++k0i) {
            const int buf = k0i & 1;
            const bool last = (k0i == 3) && (ch == 15);
            const int nmst = (k0i < 3) ? mst : mst + 128;
            const int nk0 = (k0i < 3) ? (k0i + 1) * 128 : 0;
            // A slices for THIS k0i (L2-hot; __syncthreads blocks hoisting)
            f16x8 Ah0[4], Ah1[4];
#pragma unroll
            for (int kk = 0; kk < 4; ++kk) {
                Ah0[kk] = *(const f16x8*)&qh[arow0 + (k0i * 4 + kk) * 32];
                Ah1[kk] = *(const f16x8*)&qh[arow1 + (k0i * 4 + kk) * 32];
            }
            f16x8 L[4];
            if (!last) {                        // issue next-step loads EARLY
#pragma unroll
                for (int i = 0; i < 4; ++i) {
                    int id = i * 512 + t, r = id >> 4, s = id & 15;
                    L[i] = *(const f16x8*)&qh[(size_t)(nmst + r) * 512 + nk0 + s * 8];
                }
            }
#pragma unroll
            for (int kk = 0; kk < 4; ++kk) {
                const f16x8 a0 = Ah0[kk], a1 = Ah1[kk];
#pragma unroll
                for (int tt = 0; tt < 2; ++tt) {
                    const int br = mg * 32 + tt * 16 + ln16;
                    f16x8 bb = *(const f16x8*)&Bs[buf][br][((kk * 4 + hi4) ^ ln16) * 8];
                    S[0][tt] = __builtin_amdgcn_mfma_f32_16x16x32_f16(a0, bb, S[0][tt], 0, 0, 0);
                    S[1][tt] = __builtin_amdgcn_mfma_f32_16x16x32_f16(a1, bb, S[1][tt], 0, 0, 0);
                }
            }
            if (k0i == 3) {                     // chunk complete: threshold
#pragma unroll
                for (int rt = 0; rt < 2; ++rt)
#pragma unroll
                    for (int tt = 0; tt < 2; ++tt) {
                        const int m = mst + mg * 32 + tt * 16 + ln16;
#pragma unroll
                        for (int i = 0; i < 4; ++i) {
                            float cs = S[rt][tt][i];
                            int row = rg * 32 + rt * 16 + hi4 * 4 + i;
                            if (cs > 0.1f + QBAND) {
                                int pos = atomicAdd(&cnt[row], 1);
                                if (pos < CAP2) {
                                    size_t o = ((size_t)(nb + n0 + row) * 2 + half) * CAP2 + pos;
                                    idxs[o] = (uint16_t)m;
                                    vals[o] = (bf16)cs;
                                }
                            } else if (cs > 0.1f - QBAND) {
                                int bp = atomicAdd(&bcnt, 1);
                                if (bp < BCAPC)
                                    blist[bp] = ((uint32_t)row << 12) | (uint32_t)m;
                            }
                        }
                    }
            }
            __syncthreads();           // Bs[buf^1] reads done; blist complete
            if (!last) {
#pragma unroll
                for (int i = 0; i < 4; ++i) {
                    int id = i * 512 + t, r = id >> 4, s = id & 15;
                    *(f16x8*)&Bs[buf ^ 1][r][(s ^ (r & 15)) * 8] = L[i];
                }
            }
            if (k0i == 3) {            // wave-parallel fp32/f64-acc verify
                int nbd = bcnt; if (nbd > BCAPC) nbd = BCAPC;
                for (int p = wave; p < nbd; p += 8) {
                    uint32_t pk = blist[p];
                    int row = (int)(pk >> 12), m = (int)(pk & 4095);
                    const float* qa = qf + (size_t)(n0 + row) * 512;
                    const float* qc = qf + (size_t)m * 512;
                    f4 a0 = *(const f4*)&qa[lane * 8];
                    f4 a1 = *(const f4*)&qa[lane * 8 + 4];
                    f4 c0 = *(const f4*)&qc[lane * 8];
                    f4 c1 = *(const f4*)&qc[lane * 8 + 4];
                    double s = (double)a0.x * c0.x + (double)a0.y * c0.y +
                               (double)a0.z * c0.z + (double)a0.w * c0.w +
                               (double)a1.x * c1.x + (double)a1.y * c1.y +
                               (double)a1.z * c1.z + (double)a1.w * c1.w;
                    for (int off = 1; off < 64; off <<= 1) s += __shfl_xor(s, off);
                    if (lane == 0 && s > 0.1) {
                        int pos = atomicAdd(&cnt[row], 1);
                        if (pos < CAP2) {
                            size_t o = ((size_t)(nb + n0 + row) * 2 + half) * CAP2 + pos;
                            idxs[o] = (uint16_t)m;
                            vals[o] = (bf16)(float)s;
                        }
                    }
                }
            }
            __syncthreads();           // staging writes visible; verify done
            if (k0i == 3 && t == 0) bcnt = 0;
        }
    }
    __syncthreads();
    if (t < 64) {
        int c = cnt[t];
        counts[(size_t)(nb + n0 + t) * 2 + half] = (uint16_t)(c > CAP2 ? CAP2 : c);
    }
}

// ---------------------------------------------------------------------------
// K4 (R10, proven): 32x32x16-MFMA PV + fused LayerNorm. grid 256, 512 thr.
// ---------------------------------------------------------------------------
__global__ __launch_bounds__(512, 2) void pv_mfma(const bf16* __restrict__ VT,
                                                  const uint16_t* __restrict__ counts,
                                                  const uint16_t* __restrict__ idxs,
                                                  const bf16* __restrict__ vals,
                                                  const float* __restrict__ gamma,
                                                  const float* __restrict__ beta,
                                                  float* __restrict__ Out) {
    __shared__ __align__(16) char smemraw[147456];   // Vts 128K + Wsm 16K
    bf16 (*Vts)[128] = (bf16(*)[128])smemraw;        // [512 e][128 m] swz
    bf16 (*Wsm)[128] = (bf16(*)[128])(smemraw + 131072); // [64 n][128 m] swz

    const int t = threadIdx.x;
    const int wave = t >> 6, lane = t & 63;
    const int l31 = lane & 31, l15 = lane & 15, g = lane >> 5;
    const int grp = blockIdx.x & 7;                  // XCD-pinned batch panel
    const int b = grp >> 1;
    const int n0 = ((blockIdx.x >> 3) + ((grp & 1) ? 32 : 0)) * 64;
    const size_t nb = (size_t)b * 4096;
    const bf16* vtb = VT + (size_t)b * 512 * 4096;

    int myc0 = 0, myc1 = 0, cu = 0, pb = 0;
    u16x8 pi0 = {}, pi1 = {};
    bf16x8 pv0 = {}, pv1 = {};
    size_t base0 = 0, base1 = 0;
    if (t < 64) {
        myc0 = (int)counts[(size_t)(nb + n0 + t) * 2 + 0];
        myc1 = (int)counts[(size_t)(nb + n0 + t) * 2 + 1];
        if (myc0 > CAP2) myc0 = CAP2;
        if (myc1 > CAP2) myc1 = CAP2;
        base0 = ((size_t)(nb + n0 + t) * 2 + 0) * CAP2;
        base1 = ((size_t)(nb + n0 + t) * 2 + 1) * CAP2;
        pi0 = *(const u16x8*)&idxs[base0];
        pi1 = *(const u16x8*)&idxs[base0 + 8];
        pv0 = *(const bf16x8*)&vals[base0];
        pv1 = *(const bf16x8*)&vals[base0 + 8];
    }

    bf16x8 L[16];
#pragma unroll
    for (int i = 0; i < 16; ++i) {
        int id = i * 512 + t, r = id >> 4, s = id & 15;
        L[i] = *(const bf16x8*)&vtb[(size_t)r * 4096 + s * 8];
    }

    f16v acc[2][2] = {};   // [nt][et]

    for (int ch = 0; ch < 32; ++ch) {
        __syncthreads();
#pragma unroll
        for (int i = 0; i < 16; ++i) {
            int id = i * 512 + t, r = id >> 4, s = id & 15;
            *(bf16x8*)&Vts[r][(s ^ (r & 15)) << 3] = L[i];
        }
        if (t < 64) {
            bf16 z0 = (bf16)0.0f;
            bf16x8 zv = {z0, z0, z0, z0, z0, z0, z0, z0};
#pragma unroll
            for (int sj = 0; sj < 16; ++sj) *(bf16x8*)&Wsm[t][sj * 8] = zv;
            if (ch == 16) cu = 0;
            const int m0l = ch * 128;
            const int myc = (ch >= 16) ? myc1 : myc0;
            const size_t base = (ch >= 16) ? base1 : base0;
            int end = cu;
#pragma unroll
            for (int j = 0; j < 16; ++j) {
                int pos = pb + j;
                int mi = (j < 8) ? (int)pi0[j] : (int)pi1[j - 8];
                bf16 vv = (j < 8) ? pv0[j] : pv1[j - 8];
                if (pos == end && pos < myc && mi < m0l + 128) {
                    int lo = mi - m0l;
                    Wsm[t][(((lo >> 3) ^ (t & 15)) << 3) | (lo & 7)] = vv;
                    end = pos + 1;
                }
            }
            if (end == pb + 16) {
                while (end < myc) {
                    int mi = (int)idxs[base + end];
                    if (mi >= m0l + 128) break;
                    int lo = mi - m0l;
                    Wsm[t][(((lo >> 3) ^ (t & 15)) << 3) | (lo & 7)] =
                        vals[base + end];
                    ++end;
                }
            }
            cu = end;
        }
        __syncthreads();
        if (ch < 31) {
            const int mo = (ch + 1) * 128;
#pragma unroll
            for (int i = 0; i < 16; ++i) {
                int id = i * 512 + t, r = id >> 4, s = id & 15;
                L[i] = *(const bf16x8*)&vtb[(size_t)r * 4096 + mo + s * 8];
            }
            if (t < 64) {
                int ncu = (ch + 1 == 16) ? 0 : cu;
                const size_t nbase = (ch + 1 >= 16) ? base1 : base0;
                pb = ncu & ~7;
                pi0 = *(const u16x8*)&idxs[nbase + pb];
                pi1 = *(const u16x8*)&idxs[nbase + pb + 8];
                pv0 = *(const bf16x8*)&vals[nbase + pb];
                pv1 = *(const bf16x8*)&vals[nbase + pb + 8];
            }
        }
#pragma unroll
        for (int ks = 0; ks < 8; ++ks) {
            const int sw = (((ks * 2 + g) ^ l15) << 3);
            bf16x8 A0 = *(const bf16x8*)&Wsm[l31][sw];
            bf16x8 A1 = *(const bf16x8*)&Wsm[32 + l31][sw];
            bf16x8 B0 = *(const bf16x8*)&Vts[wave * 64 + l31][sw];
            bf16x8 B1 = *(const bf16x8*)&Vts[wave * 64 + 32 + l31][sw];
            acc[0][0] = __builtin_amdgcn_mfma_f32_32x32x16_bf16(A0, B0, acc[0][0], 0, 0, 0);
            acc[0][1] = __builtin_amdgcn_mfma_f32_32x32x16_bf16(A0, B1, acc[0][1], 0, 0, 0);
            acc[1][0] = __builtin_amdgcn_mfma_f32_32x32x16_bf16(A1, B0, acc[1][0], 0, 0, 0);
            acc[1][1] = __builtin_amdgcn_mfma_f32_32x32x16_bf16(A1, B1, acc[1][1], 0, 0, 0);
        }
    }

    // ---- fused LayerNorm over 512 cols ----
    __syncthreads();
    float* red = (float*)smemraw;            // [8][64][2]
    float* mrs = (float*)(smemraw + 4096);   // mu[64], rs[64]
#pragma unroll
    for (int nt = 0; nt < 2; ++nt)
#pragma unroll
        for (int r = 0; r < 16; ++r) {
            float v0 = acc[nt][0][r], v1 = acc[nt][1][r];
            float s = v0 + v1, q = v0 * v0 + v1 * v1;
            for (int off = 1; off < 32; off <<= 1) {
                s += __shfl_xor(s, off);
                q += __shfl_xor(q, off);
            }
            if (l31 == 0) {
                int nloc = nt * 32 + (r & 3) + 8 * (r >> 2) + 4 * g;
                red[(wave * 64 + nloc) * 2] = s;
                red[(wave * 64 + nloc) * 2 + 1] = q;
            }
        }
    __syncthreads();
    if (t < 64) {
        float s = 0.f, q = 0.f;
        for (int w2 = 0; w2 < 8; ++w2) {
            s += red[(w2 * 64 + t) * 2];
            q += red[(w2 * 64 + t) * 2 + 1];
        }
        float mu = s * (1.0f / 512.0f);
        float var = q * (1.0f / 512.0f) - mu * mu;
        mrs[t] = mu;
        mrs[64 + t] = rsqrtf(var + 1e-5f);
    }
    __syncthreads();
    const float g0 = gamma[wave * 64 + l31], g1 = gamma[wave * 64 + 32 + l31];
    const float b0 = beta[wave * 64 + l31], b1 = beta[wave * 64 + 32 + l31];
#pragma unroll
    for (int nt = 0; nt < 2; ++nt)
#pragma unroll
        for (int r = 0; r < 16; ++r) {
            int nloc = nt * 32 + (r & 3) + 8 * (r >> 2) + 4 * g;
            float mu = mrs[nloc], rs = mrs[64 + nloc];
            size_t ro = (nb + n0 + nloc) * 512;
            float y0 = (acc[nt][0][r] - mu) * rs * g0 + b0;
            float y1 = (acc[nt][1][r] - mu) * rs * g1 + b1;
            Out[ro + wave * 64 + l31] = y0;
            Out[ro + wave * 64 + 32 + l31] = y1;
        }
}

// ---------------------------------------------------------------------------
extern "C" void kernel_launch(void* const* d_in, const int* in_sizes, int n_in,
                              void* d_out, int out_size, void* d_ws, size_t ws_size,
                              hipStream_t stream) {
    const float* x     = (const float*)d_in[0];
    const float* wqk   = (const float*)d_in[1];
    const float* wv    = (const float*)d_in[2];
    const float* gamma = (const float*)d_in[3];
    const float* beta  = (const float*)d_in[4];
    float* out = (float*)d_out;

    char* ws = (char*)d_ws;
    uint16_t* idxs   = (uint16_t*)ws;                        // 33,554,432 B
    bf16*     vals   = (bf16*)(ws + 33554432);               // -> 67,108,864
    float*    qn32   = (float*)(ws + 67108864);              // -> 100,663,296 (Q fp32, normalized in-place)
    f16*      qh16   = (f16*)(ws + 100663296);               // -> 117,440,512
    // [117,440,512 .. 134,217,728) dead
    bf16*     vt     = (bf16*)(ws + 134217728);              // -> 150,994,944
    uint16_t* counts = (uint16_t*)(ws + 150994944);          // -> 151,060,480
    const size_t need = 151060480;  // == R2-proven ws_size lower bound
    if (ws_size < need) return;

    proj_q16<<<256, 512, 0, stream>>>(x, wqk, qn32);
    proj_v16<<<dim3(128, 8), 256, 0, stream>>>(x, wv, vt);
    norm_q<<<4096, 256, 0, stream>>>(qn32, qh16);
    qk_mfma<<<512, 512, 0, stream>>>(qn32, qh16, counts, idxs, vals);
    pv_mfma<<<256, 512, 0, stream>>>(vt, counts, idxs, vals, gamma, beta, out);
}